// Round 5
// baseline (168.958 us; speedup 1.0000x reference)
//
#include <hip/hip_runtime.h>

#define NB 256
#define NO 10
#define NI 1152
#define NK 8
#define ND 16
#define PCH 72    // chunks for pass0/acc (IC=16)
#define PIC 16
#define DCH 144   // chunks for dotsoft (IC=8)
#define DIC 8

typedef unsigned short u16;
typedef unsigned int u32;
typedef __attribute__((ext_vector_type(8))) short s8v;   // 8 bf16 = 4 VGPR (MFMA A/B frag)
typedef __attribute__((ext_vector_type(4))) float f4v;   // MFMA C/D frag

__device__ __forceinline__ u16 f2bf(float f){
  u32 u = __float_as_uint(f);
  return (u16)((u + 0x7FFFu + ((u >> 16) & 1u)) >> 16);  // RNE
}
__device__ __forceinline__ float bf2f(u16 h){ return __uint_as_float(((u32)h) << 16); }
__device__ __forceinline__ s8v zero8(){
  s8v z;
  #pragma unroll
  for (int j = 0; j < 8; ++j) z[j] = 0;
  return z;
}

// One-time: xb = bf16(x) (same layout), Wb = bf16(W), WTb[o,i,k,d] = bf16(W[o,i,d,k])
__global__ __launch_bounds__(256) void k_prep(const float* __restrict__ x,
                                              const float* __restrict__ W,
                                              u16* __restrict__ xb,
                                              u16* __restrict__ Wb,
                                              u16* __restrict__ WTb){
  int t = blockIdx.x * 256 + threadIdx.x;
  const int NX = NB * NI * NK;
  for (int idx = t; idx < NX; idx += gridDim.x * 256) xb[idx] = f2bf(x[idx]);
  const int NW = NO * NI * ND * NK;
  for (int idx = t; idx < NW; idx += gridDim.x * 256){
    u16 h = f2bf(W[idx]);
    Wb[idx] = h;
    int k = idx & 7, d = (idx >> 3) & 15, oi = idx >> 7;
    WTb[((size_t)oi * NK + k) * ND + d] = h;
  }
}

// Iter0: per-i u-tiles via MFMA (K=8 in 32). Epilogue: usq[o,i,b]; P[ch,o,d,b] = 0.1*sum_i u
__global__ __launch_bounds__(256) void k_pass0(const u16* __restrict__ xb,
                                               const u16* __restrict__ Wb,
                                               float* __restrict__ usq,
                                               float* __restrict__ P){
  int ch = blockIdx.x, o = blockIdx.y, i0 = ch * PIC;
  int w = threadIdx.x >> 6, l = threadIdx.x & 63, g = l >> 4, col = l & 15;
  float s0[4][4];
  #pragma unroll
  for (int bt = 0; bt < 4; ++bt){
    #pragma unroll
    for (int j = 0; j < 4; ++j) s0[bt][j] = 0.f;
  }
  for (int ii = 0; ii < PIC; ++ii){
    int i = i0 + ii;
    s8v a = zero8();
    if (g == 0)  // A[d=col][k=j], rows=d, K valid 0..7
      a = *(const s8v*)(Wb + ((size_t)(o * NI + i) * ND + col) * NK);
    #pragma unroll
    for (int bt = 0; bt < 4; ++bt){
      int b = (w * 4 + bt) * 16 + col;
      s8v bf = zero8();
      if (g == 0)  // B[k=j][n=col] = x[b][i][j]
        bf = *(const s8v*)(xb + ((size_t)b * NI + i) * NK);
      f4v c = {0.f, 0.f, 0.f, 0.f};
      c = __builtin_amdgcn_mfma_f32_16x16x32_bf16(a, bf, c, 0, 0, 0);
      float uq = c[0]*c[0] + c[1]*c[1] + c[2]*c[2] + c[3]*c[3];
      uq += __shfl_xor(uq, 16);
      uq += __shfl_xor(uq, 32);
      if (g == 0) usq[((size_t)o * NI + i) * NB + b] = uq;
      #pragma unroll
      for (int j = 0; j < 4; ++j) s0[bt][j] += c[j];
    }
  }
  #pragma unroll
  for (int bt = 0; bt < 4; ++bt){
    int b = (w * 4 + bt) * 16 + col;
    #pragma unroll
    for (int j = 0; j < 4; ++j)
      P[(((size_t)ch * NO + o) * ND + (4 * g + j)) * NB + b] = 0.1f * s0[bt][j];
  }
}

// Reduce P -> S (fp32), Sbt (bf16 [o][b][d]), s2 partials per d-quarter
__global__ __launch_bounds__(256) void k_red(const float* __restrict__ P,
                                             float* __restrict__ S,
                                             u16* __restrict__ Sbt,
                                             float* __restrict__ s2p){
  int o = blockIdx.x, dq = blockIdx.y, b = threadIdx.x;
  float s2 = 0.f;
  u32 pk[2];
  #pragma unroll
  for (int jd = 0; jd < 4; ++jd){
    int d = dq * 4 + jd;
    float a = 0.f;
    for (int ch = 0; ch < PCH; ++ch)
      a += P[(((size_t)ch * NO + o) * ND + d) * NB + b];
    S[((size_t)o * ND + d) * NB + b] = a;
    s2 = fmaf(a, a, s2);
    u32 h = f2bf(a);
    if (jd & 1) pk[jd >> 1] |= h << 16; else pk[jd >> 1] = h;
  }
  *(uint2*)(Sbt + ((size_t)o * NB + b) * ND + dq * 4) = make_uint2(pk[0], pk[1]);
  s2p[((size_t)dq * NO + o) * NB + b] = s2;
}

// Fused dot (MFMA T = W^T S) + db + L-update + softmax -> C
template<bool FIRST>
__global__ __launch_bounds__(256) void k_dotsoft(const float* __restrict__ x,
                                                 const u16* __restrict__ WTb,
                                                 const u16* __restrict__ Sbt,
                                                 const float* __restrict__ s2p,
                                                 const float* __restrict__ usq,
                                                 float* __restrict__ L,
                                                 float* __restrict__ C){
  int ch = blockIdx.x, ibase = ch * DIC;
  int w = threadIdx.x >> 6, l = threadIdx.x & 63, g = l >> 4, col = l & 15;
  int b = (blockIdx.y * 4 + w) * 16 + col;
  // Hoist B-frags (S tiles) and |S|^2 per o
  s8v sb[NO];
  float s2v[NO];
  #pragma unroll
  for (int o = 0; o < NO; ++o){
    sb[o] = zero8();
    if (g < 2)  // B[kd=8g+j][n=col] = S[o][d][b]
      sb[o] = *(const s8v*)(Sbt + ((size_t)o * NB + b) * ND + 8 * g);
    float s2 = 0.f;
    #pragma unroll
    for (int q = 0; q < 4; ++q) s2 += s2p[((size_t)q * NO + o) * NB + b];
    s2v[o] = s2;
  }
  for (int ip = 0; ip < DIC / 2; ++ip){
    int i0 = ibase + 2 * ip;
    int i = i0 + (g >> 1);          // this lane's i for epilogue rows
    int kb = 4 * (g & 1);
    float4 xv = *(const float4*)(x + ((size_t)b * NI + i) * NK + kb);
    float dots[NO];
    #pragma unroll
    for (int o = 0; o < NO; ++o){
      s8v a = zero8();
      if (g < 2){                   // A[r=col][kd=8g+j] = WTb[o][i(r)][k(r)][d]
        int ia = i0 + (col >> 3), ka = col & 7;
        a = *(const s8v*)(WTb + (((size_t)(o * NI + ia)) * NK + ka) * ND + 8 * g);
      }
      f4v c = {0.f, 0.f, 0.f, 0.f};
      c = __builtin_amdgcn_mfma_f32_16x16x32_bf16(a, sb[o], c, 0, 0, 0);
      // C rows 4g+j = (i = i0 + (row>>3), k = row&7); matches (i, kb..kb+3)
      float p = c[0] * xv.x + c[1] * xv.y + c[2] * xv.z + c[3] * xv.w;
      p += __shfl_xor(p, 16);       // g0+g1 -> dot(i0); g2+g3 -> dot(i1)
      dots[o] = p;
    }
    float lg[NO];
    #pragma unroll
    for (int o = 0; o < NO; ++o){
      float us = usq[((size_t)o * NI + i) * NB + b];
      float t2 = fmaxf(s2v[o] - 2.f * dots[o] + us, 0.f);
      float ut = dots[o] - us;
      float db = (t2 / (1.f + t2)) * ut / (sqrtf(t2) + 1e-8f);
      float lo = FIRST ? db : (L[((size_t)o * NI + i) * NB + b] + db);
      if (FIRST && ((g & 1) == 0)) L[((size_t)o * NI + i) * NB + b] = lo;
      lg[o] = lo;
    }
    float m = lg[0];
    #pragma unroll
    for (int o = 1; o < NO; ++o) m = fmaxf(m, lg[o]);
    float den = 0.f;
    #pragma unroll
    for (int o = 0; o < NO; ++o){ lg[o] = __expf(lg[o] - m); den += lg[o]; }
    float inv = 1.f / den;
    if ((g & 1) == 0){
      #pragma unroll
      for (int o = 0; o < NO; ++o)
        C[((size_t)o * NI + i) * NB + b] = lg[o] * inv;
    }
  }
}

// Dense split-K GEMM: P[ch,o,d,b] = sum_{i in chunk, k} W[o,i,d,k] * (c*x)[b,i,k]
__global__ __launch_bounds__(256) void k_acc(const u16* __restrict__ xb,
                                             const u16* __restrict__ Wb,
                                             const float* __restrict__ C,
                                             float* __restrict__ P){
  int ch = blockIdx.x, o = blockIdx.y, i0 = ch * PIC;
  int w = threadIdx.x >> 6, l = threadIdx.x & 63, g = l >> 4, col = l & 15;
  f4v cacc[4];
  #pragma unroll
  for (int bt = 0; bt < 4; ++bt) cacc[bt] = (f4v){0.f, 0.f, 0.f, 0.f};
  for (int kt = 0; kt < PIC / 4; ++kt){
    int ia = i0 + kt * 4;
    int il = ia + g;                // this lane's i for A and B
    // A[d=col][k=8g+j] -> (ii=g, k=j)
    s8v a = *(const s8v*)(Wb + ((size_t)(o * NI + il) * ND + col) * NK);
    #pragma unroll
    for (int bt = 0; bt < 4; ++bt){
      int b = (w * 4 + bt) * 16 + col;
      float cw = C[((size_t)o * NI + il) * NB + b];
      s8v xv = *(const s8v*)(xb + ((size_t)b * NI + il) * NK);
      s8v bb;
      #pragma unroll
      for (int j = 0; j < 8; ++j)
        bb[j] = (short)f2bf(bf2f((u16)xv[j]) * cw);
      cacc[bt] = __builtin_amdgcn_mfma_f32_16x16x32_bf16(a, bb, cacc[bt], 0, 0, 0);
    }
  }
  #pragma unroll
  for (int bt = 0; bt < 4; ++bt){
    int b = (w * 4 + bt) * 16 + col;
    #pragma unroll
    for (int j = 0; j < 4; ++j)
      P[(((size_t)ch * NO + o) * ND + (4 * g + j)) * NB + b] = cacc[bt][j];
  }
}

// out[b][o][d] = squash(S[o,:,b])
__global__ __launch_bounds__(256) void k_final(const float* __restrict__ S,
                                               float* __restrict__ out){
  int o = blockIdx.x, b = threadIdx.x;
  float s[ND], s2 = 0.f;
  #pragma unroll
  for (int d = 0; d < ND; ++d){
    s[d] = S[((size_t)o * ND + d) * NB + b];
    s2 = fmaf(s[d], s[d], s2);
  }
  float sc = (s2 / (1.f + s2)) / (sqrtf(s2) + 1e-8f);
  #pragma unroll
  for (int d = 0; d < ND; ++d) out[((size_t)b * NO + o) * ND + d] = s[d] * sc;
}

extern "C" void kernel_launch(void* const* d_in, const int* in_sizes, int n_in,
                              void* d_out, int out_size, void* d_ws, size_t ws_size,
                              hipStream_t stream){
  const float* x = (const float*)d_in[0];
  // d_in[1] (y) unused by the reference computation.
  const float* W = (const float*)d_in[2];
  float* out = (float*)d_out;
  char* ws = (char*)d_ws;

  const size_t xb_b  = (size_t)NB * NI * NK * sizeof(u16);            // 4.7 MB
  const size_t Wb_b  = (size_t)NO * NI * ND * NK * sizeof(u16);       // 2.95 MB
  const size_t usq_b = (size_t)NO * NI * NB * sizeof(float);          // 11.8 MB
  const size_t P_b   = (size_t)PCH * NO * ND * NB * sizeof(float);    // 11.8 MB
  const size_t S_b   = (size_t)NO * ND * NB * sizeof(float);          // 160 KB
  const size_t Sbt_b = (size_t)NO * NB * ND * sizeof(u16);            // 80 KB
  const size_t s2p_b = (size_t)4 * NO * NB * sizeof(float);           // 40 KB

  size_t off = 0;
  u16*   xb  = (u16*)(ws + off);   off += xb_b;
  u16*   Wb  = (u16*)(ws + off);   off += Wb_b;
  u16*   WTb = (u16*)(ws + off);   off += Wb_b;
  float* usq = (float*)(ws + off); off += usq_b;
  float* L   = (float*)(ws + off); off += usq_b;
  float* C   = (float*)(ws + off); off += usq_b;
  float* P   = (float*)(ws + off); off += P_b;
  float* S   = (float*)(ws + off); off += S_b;
  u16*   Sbt = (u16*)(ws + off);   off += Sbt_b;
  float* s2p = (float*)(ws + off); off += s2p_b;
  (void)ws_size; (void)in_sizes; (void)n_in; (void)out_size;

  k_prep<<<dim3(1024), 256, 0, stream>>>(x, W, xb, Wb, WTb);

  // iter 0: uniform c = 0.1 -> S0, usq
  k_pass0<<<dim3(PCH, NO), 256, 0, stream>>>(xb, Wb, usq, P);
  k_red<<<dim3(NO, 4), 256, 0, stream>>>(P, S, Sbt, s2p);
  k_dotsoft<true><<<dim3(DCH, 4), 256, 0, stream>>>(x, WTb, Sbt, s2p, usq, L, C);

  // iter 1
  k_acc<<<dim3(PCH, NO), 256, 0, stream>>>(xb, Wb, C, P);
  k_red<<<dim3(NO, 4), 256, 0, stream>>>(P, S, Sbt, s2p);
  k_dotsoft<false><<<dim3(DCH, 4), 256, 0, stream>>>(x, WTb, Sbt, s2p, usq, L, C);

  // iter 2 (final accumulation) + squash
  k_acc<<<dim3(PCH, NO), 256, 0, stream>>>(xb, Wb, C, P);
  k_red<<<dim3(NO, 4), 256, 0, stream>>>(P, S, Sbt, s2p);
  k_final<<<dim3(NO), 256, 0, stream>>>(S, out);
}

// Round 6
// 135.811 us; speedup vs baseline: 1.2441x; 1.2441x over previous
//
#include <hip/hip_runtime.h>

#define NB 256
#define NO 10
#define NI 1152
#define NK 8
#define ND 16
#define PCH 72    // chunks for pass0/acc (IC=16)
#define PIC 16
#define DCH 144   // chunks for dotsoft (IC=8)
#define DIC 8

typedef unsigned short u16;
typedef unsigned int u32;
typedef __attribute__((ext_vector_type(8))) short s8v;   // 8 bf16 = 4 VGPR (MFMA A/B frag)
typedef __attribute__((ext_vector_type(4))) float f4v;   // MFMA C/D frag

__device__ __forceinline__ u16 f2bf(float f){
  u32 u = __float_as_uint(f);
  return (u16)((u + 0x7FFFu + ((u >> 16) & 1u)) >> 16);  // RNE
}
__device__ __forceinline__ float bf2f(u16 h){ return __uint_as_float(((u32)h) << 16); }
__device__ __forceinline__ s8v zero8(){
  s8v z;
  #pragma unroll
  for (int j = 0; j < 8; ++j) z[j] = 0;
  return z;
}

// One-time: xbf[i][b][k] = bf16(x[b][i][k]); Wb = bf16(W) [o][i][d][k]; WTb [o][i][k][d]
__global__ __launch_bounds__(256) void k_prep(const float* __restrict__ x,
                                              const float* __restrict__ W,
                                              u16* __restrict__ xbf,
                                              u16* __restrict__ Wb,
                                              u16* __restrict__ WTb){
  int t = blockIdx.x * 256 + threadIdx.x;
  const int NX = NI * NB * NK;
  for (int idx = t; idx < NX; idx += gridDim.x * 256){
    int k = idx & 7, b = (idx >> 3) & (NB - 1), i = idx >> 11;   // NB*NK = 2048
    xbf[idx] = f2bf(x[((size_t)b * NI + i) * NK + k]);
  }
  const int NW = NO * NI * ND * NK;
  for (int idx = t; idx < NW; idx += gridDim.x * 256){
    u16 h = f2bf(W[idx]);
    Wb[idx] = h;
    int k = idx & 7, d = (idx >> 3) & 15, oi = idx >> 7;
    WTb[((size_t)oi * NK + k) * ND + d] = h;
  }
}

// Iter0: per-i u-tiles via MFMA (K=8 in 32). Epilogue: usq[o,i,b]; P[o,d,ch,b] = 0.1*sum_i u
__global__ __launch_bounds__(256) void k_pass0(const u16* __restrict__ xbf,
                                               const u16* __restrict__ Wb,
                                               float* __restrict__ usq,
                                               float* __restrict__ P){
  int ch = blockIdx.x, o = blockIdx.y, i0 = ch * PIC;
  int w = threadIdx.x >> 6, l = threadIdx.x & 63, g = l >> 4, col = l & 15;
  float s0[4][4];
  #pragma unroll
  for (int bt = 0; bt < 4; ++bt){
    #pragma unroll
    for (int j = 0; j < 4; ++j) s0[bt][j] = 0.f;
  }
  for (int ii = 0; ii < PIC; ++ii){
    int i = i0 + ii;
    s8v a = zero8();
    if (g == 0)  // A[d=col][k=j]
      a = *(const s8v*)(Wb + ((size_t)(o * NI + i) * ND + col) * NK);
    #pragma unroll
    for (int bt = 0; bt < 4; ++bt){
      int b = (w * 4 + bt) * 16 + col;
      s8v bf = zero8();
      if (g == 0)  // B[k=j][n=col] = x[b][i][j]  (contiguous: lanes consecutive b)
        bf = *(const s8v*)(xbf + ((size_t)i * NB + b) * NK);
      f4v c = {0.f, 0.f, 0.f, 0.f};
      c = __builtin_amdgcn_mfma_f32_16x16x32_bf16(a, bf, c, 0, 0, 0);
      float uq = c[0]*c[0] + c[1]*c[1] + c[2]*c[2] + c[3]*c[3];
      uq += __shfl_xor(uq, 16);
      uq += __shfl_xor(uq, 32);
      if (g == 0) usq[((size_t)o * NI + i) * NB + b] = uq;
      #pragma unroll
      for (int j = 0; j < 4; ++j) s0[bt][j] += c[j];
    }
  }
  #pragma unroll
  for (int bt = 0; bt < 4; ++bt){
    int b = (w * 4 + bt) * 16 + col;
    #pragma unroll
    for (int j = 0; j < 4; ++j)
      P[(((size_t)o * ND + (4 * g + j)) * PCH + ch) * NB + b] = 0.1f * s0[bt][j];
  }
}

// Reduce P over ch.  LAST: write fp32 S (for k_final); else write bf16 Sbt [o][b][d]
template<bool LAST>
__global__ __launch_bounds__(256) void k_red(const float* __restrict__ P,
                                             u16* __restrict__ Sbt,
                                             float* __restrict__ S){
  int o = blockIdx.x, d = blockIdx.y, b = threadIdx.x;
  const float* p = P + ((size_t)o * ND + d) * PCH * NB + b;
  float a0 = 0.f, a1 = 0.f, a2 = 0.f, a3 = 0.f;
  #pragma unroll
  for (int ch = 0; ch < PCH; ch += 4){
    a0 += p[(size_t)ch * NB];
    a1 += p[(size_t)(ch + 1) * NB];
    a2 += p[(size_t)(ch + 2) * NB];
    a3 += p[(size_t)(ch + 3) * NB];
  }
  float a = (a0 + a1) + (a2 + a3);
  if (LAST) S[((size_t)o * ND + d) * NB + b] = a;
  else      Sbt[((size_t)o * NB + b) * ND + d] = f2bf(a);
}

// Fused dot (MFMA T = W^T S) + db + L-update + softmax -> C
template<bool FIRST>
__global__ __launch_bounds__(256) void k_dotsoft(const u16* __restrict__ xbf,
                                                 const u16* __restrict__ WTb,
                                                 const u16* __restrict__ Sbt,
                                                 const float* __restrict__ usq,
                                                 float* __restrict__ L,
                                                 float* __restrict__ C){
  int ch = blockIdx.x, ibase = ch * DIC;
  int w = threadIdx.x >> 6, l = threadIdx.x & 63, g = l >> 4, col = l & 15;
  int b = (blockIdx.y * 4 + w) * 16 + col;
  // Hoist B-frags (S tiles); |S|^2 from the frags via shfl (g0:d0-7, g1:d8-15)
  s8v sb[NO];
  float s2v[NO];
  #pragma unroll
  for (int o = 0; o < NO; ++o){
    sb[o] = zero8();
    if (g < 2)
      sb[o] = *(const s8v*)(Sbt + ((size_t)o * NB + b) * ND + 8 * g);
    float s2 = 0.f;
    #pragma unroll
    for (int j = 0; j < 8; ++j){
      float v = bf2f((u16)sb[o][j]);
      s2 = fmaf(v, v, s2);
    }
    s2 += __shfl_xor(s2, 16);
    s2 += __shfl_xor(s2, 32);
    s2v[o] = s2;
  }
  for (int ip = 0; ip < DIC / 2; ++ip){
    int i0 = ibase + 2 * ip;
    int i = i0 + (g >> 1);          // this lane's i for epilogue rows
    int kb = 4 * (g & 1);
    ushort4 xq = *(const ushort4*)(xbf + ((size_t)i * NB + b) * NK + kb);
    float dots[NO];
    #pragma unroll
    for (int o = 0; o < NO; ++o){
      s8v a = zero8();
      if (g < 2){                   // A[r=col][kd=8g+j] = WTb[o][i(r)][k(r)][d]
        int ia = i0 + (col >> 3), ka = col & 7;
        a = *(const s8v*)(WTb + (((size_t)(o * NI + ia)) * NK + ka) * ND + 8 * g);
      }
      f4v c = {0.f, 0.f, 0.f, 0.f};
      c = __builtin_amdgcn_mfma_f32_16x16x32_bf16(a, sb[o], c, 0, 0, 0);
      // C rows 4g+j = (i = i0 + (row>>3), k = row&7); matches (i, kb..kb+3)
      float p = c[0] * bf2f(xq.x) + c[1] * bf2f(xq.y)
              + c[2] * bf2f(xq.z) + c[3] * bf2f(xq.w);
      p += __shfl_xor(p, 16);       // g0+g1 -> dot(i0); g2+g3 -> dot(i1)
      dots[o] = p;
    }
    float lg[NO];
    #pragma unroll
    for (int o = 0; o < NO; ++o){
      float us = usq[((size_t)o * NI + i) * NB + b];
      float t2 = fmaxf(s2v[o] - 2.f * dots[o] + us, 0.f);
      float ut = dots[o] - us;
      float db = (t2 / (1.f + t2)) * ut / (sqrtf(t2) + 1e-8f);
      float lo = FIRST ? db : (L[((size_t)o * NI + i) * NB + b] + db);
      if (FIRST && ((g & 1) == 0)) L[((size_t)o * NI + i) * NB + b] = lo;
      lg[o] = lo;
    }
    float m = lg[0];
    #pragma unroll
    for (int o = 1; o < NO; ++o) m = fmaxf(m, lg[o]);
    float den = 0.f;
    #pragma unroll
    for (int o = 0; o < NO; ++o){ lg[o] = __expf(lg[o] - m); den += lg[o]; }
    float inv = 1.f / den;
    if ((g & 1) == 0){
      #pragma unroll
      for (int o = 0; o < NO; ++o)
        C[((size_t)o * NI + i) * NB + b] = lg[o] * inv;
    }
  }
}

// Dense split-K GEMM: P[o,d,ch,b] = sum_{i in chunk, k} W[o,i,d,k] * (c*x)[b,i,k]
__global__ __launch_bounds__(256) void k_acc(const u16* __restrict__ xbf,
                                             const u16* __restrict__ Wb,
                                             const float* __restrict__ C,
                                             float* __restrict__ P){
  int ch = blockIdx.x, o = blockIdx.y, i0 = ch * PIC;
  int w = threadIdx.x >> 6, l = threadIdx.x & 63, g = l >> 4, col = l & 15;
  f4v cacc[4];
  #pragma unroll
  for (int bt = 0; bt < 4; ++bt) cacc[bt] = (f4v){0.f, 0.f, 0.f, 0.f};
  for (int kt = 0; kt < PIC / 4; ++kt){
    int il = i0 + kt * 4 + g;       // this lane's i for A and B (K packs 4 i's)
    // A[d=col][k=8g+j] = W[o][il][col][j]
    s8v a = *(const s8v*)(Wb + ((size_t)(o * NI + il) * ND + col) * NK);
    #pragma unroll
    for (int bt = 0; bt < 4; ++bt){
      int b = (w * 4 + bt) * 16 + col;
      float cw = C[((size_t)o * NI + il) * NB + b];
      s8v xv = *(const s8v*)(xbf + ((size_t)il * NB + b) * NK);
      s8v bb;
      #pragma unroll
      for (int j = 0; j < 8; ++j)
        bb[j] = (short)f2bf(bf2f((u16)xv[j]) * cw);
      cacc[bt] = __builtin_amdgcn_mfma_f32_16x16x32_bf16(a, bb, cacc[bt], 0, 0, 0);
    }
  }
  #pragma unroll
  for (int bt = 0; bt < 4; ++bt){
    int b = (w * 4 + bt) * 16 + col;
    #pragma unroll
    for (int j = 0; j < 4; ++j)
      P[(((size_t)o * ND + (4 * g + j)) * PCH + ch) * NB + b] = cacc[bt][j];
  }
}

// out[b][o][d] = squash(S[o,:,b])
__global__ __launch_bounds__(256) void k_final(const float* __restrict__ S,
                                               float* __restrict__ out){
  int o = blockIdx.x, b = threadIdx.x;
  float s[ND], s2 = 0.f;
  #pragma unroll
  for (int d = 0; d < ND; ++d){
    s[d] = S[((size_t)o * ND + d) * NB + b];
    s2 = fmaf(s[d], s[d], s2);
  }
  float sc = (s2 / (1.f + s2)) / (sqrtf(s2) + 1e-8f);
  #pragma unroll
  for (int d = 0; d < ND; ++d) out[((size_t)b * NO + o) * ND + d] = s[d] * sc;
}

extern "C" void kernel_launch(void* const* d_in, const int* in_sizes, int n_in,
                              void* d_out, int out_size, void* d_ws, size_t ws_size,
                              hipStream_t stream){
  const float* x = (const float*)d_in[0];
  // d_in[1] (y) unused by the reference computation.
  const float* W = (const float*)d_in[2];
  float* out = (float*)d_out;
  char* ws = (char*)d_ws;

  const size_t xbf_b = (size_t)NI * NB * NK * sizeof(u16);            // 4.7 MB
  const size_t Wb_b  = (size_t)NO * NI * ND * NK * sizeof(u16);       // 2.95 MB
  const size_t usq_b = (size_t)NO * NI * NB * sizeof(float);          // 11.8 MB
  const size_t P_b   = (size_t)NO * ND * PCH * NB * sizeof(float);    // 11.8 MB
  const size_t S_b   = (size_t)NO * ND * NB * sizeof(float);          // 160 KB
  const size_t Sbt_b = (size_t)NO * NB * ND * sizeof(u16);            // 80 KB

  size_t off = 0;
  u16*   xbf = (u16*)(ws + off);   off += xbf_b;
  u16*   Wb  = (u16*)(ws + off);   off += Wb_b;
  u16*   WTb = (u16*)(ws + off);   off += Wb_b;
  float* usq = (float*)(ws + off); off += usq_b;
  float* L   = (float*)(ws + off); off += usq_b;
  float* C   = (float*)(ws + off); off += usq_b;
  float* P   = (float*)(ws + off); off += P_b;
  float* S   = (float*)(ws + off); off += S_b;
  u16*   Sbt = (u16*)(ws + off);   off += Sbt_b;
  (void)ws_size; (void)in_sizes; (void)n_in; (void)out_size;

  k_prep<<<dim3(1024), 256, 0, stream>>>(x, W, xbf, Wb, WTb);

  // iter 0: uniform c = 0.1 -> S0 (partials), usq
  k_pass0<<<dim3(PCH, NO), 256, 0, stream>>>(xbf, Wb, usq, P);
  k_red<false><<<dim3(NO, ND), 256, 0, stream>>>(P, Sbt, S);
  k_dotsoft<true><<<dim3(DCH, 4), 256, 0, stream>>>(xbf, WTb, Sbt, usq, L, C);

  // iter 1
  k_acc<<<dim3(PCH, NO), 256, 0, stream>>>(xbf, Wb, C, P);
  k_red<false><<<dim3(NO, ND), 256, 0, stream>>>(P, Sbt, S);
  k_dotsoft<false><<<dim3(DCH, 4), 256, 0, stream>>>(xbf, WTb, Sbt, usq, L, C);

  // iter 2 (final accumulation) + squash
  k_acc<<<dim3(PCH, NO), 256, 0, stream>>>(xbf, Wb, C, P);
  k_red<true><<<dim3(NO, ND), 256, 0, stream>>>(P, Sbt, S);
  k_final<<<dim3(NO), 256, 0, stream>>>(S, out);
}